// Round 1
// baseline (5275.072 us; speedup 1.0000x reference)
//
#include <hip/hip_runtime.h>
#include <hip/hip_bf16.h>

constexpr int B   = 4;
constexpr int N   = 1024;
constexpr int D   = 128;
constexpr int KNN = 10;
constexpr int NH  = 4;

// ---------------------------------------------------------------- norm p2d
__global__ __launch_bounds__(256) void k_norm2d(const float* __restrict__ p2d,
                                                float* __restrict__ f2) {
  int i = blockIdx.x * 256 + threadIdx.x;  // over B*N
  const float* p = p2d + (size_t)i * 3;
  float x = p[0], y = p[1], z = p[2];
  float inr = 1.f / sqrtf(x * x + y * y + z * z);
  float* o = f2 + (size_t)i * 3;
  o[0] = x * inr; o[1] = y * inr; o[2] = z * inr;
}

// ---------------------------------------------------------------- KNN encode
// grid (N, B), 256 thr. desc: [B][D][N] base for this set.
__global__ __launch_bounds__(256) void k_encode(const float* __restrict__ pts,
                                                const float* __restrict__ w,
                                                const float* __restrict__ bias,
                                                float* __restrict__ desc) {
  __shared__ float P[N][3];
  __shared__ float xx[N];
  __shared__ float dist[N];
  __shared__ float rv[256];
  __shared__ int   ri[256];
  __shared__ float feat[6];
  __shared__ int   nidx[KNN];
  int t = threadIdx.x;
  int n = blockIdx.x, b = blockIdx.y;
  const float* pb = pts + (size_t)b * N * 3;
  for (int i = t; i < N; i += 256) {
    float x = pb[i * 3 + 0], y = pb[i * 3 + 1], z = pb[i * 3 + 2];
    P[i][0] = x; P[i][1] = y; P[i][2] = z;
    xx[i] = x * x + y * y + z * z;
  }
  __syncthreads();
  float cx = P[n][0], cy = P[n][1], cz = P[n][2], cxx = xx[n];
  for (int i = t; i < N; i += 256) {
    float ip = cx * P[i][0] + cy * P[i][1] + cz * P[i][2];
    dist[i] = 2.f * ip - cxx - xx[i];
  }
  __syncthreads();
  for (int kk = 0; kk < KNN; ++kk) {
    float bv = -3.0e38f; int bi = N;
    for (int i = t; i < N; i += 256) {
      float v = dist[i];
      if (v > bv) { bv = v; bi = i; }   // ascending i -> keeps lowest idx on tie
    }
    rv[t] = bv; ri[t] = bi;
    __syncthreads();
    for (int s = 128; s > 0; s >>= 1) {
      if (t < s) {
        float v2 = rv[t + s]; int i2 = ri[t + s];
        if (v2 > rv[t] || (v2 == rv[t] && i2 < ri[t])) { rv[t] = v2; ri[t] = i2; }
      }
      __syncthreads();
    }
    if (t == 0) { nidx[kk] = ri[0]; dist[ri[0]] = -3.0e38f; }
    __syncthreads();
  }
  if (t == 0) {
    float sx = 0, sy = 0, sz = 0;
    for (int kk = 0; kk < KNN; ++kk) {
      int i = nidx[kk];
      sx += P[i][0]; sy += P[i][1]; sz += P[i][2];
    }
    const float invk = 1.f / KNN;
    feat[0] = sx * invk - cx; feat[1] = sy * invk - cy; feat[2] = sz * invk - cz;
    feat[3] = cx; feat[4] = cy; feat[5] = cz;
  }
  __syncthreads();
  if (t < D) {
    const float* wr = w + t * 6;
    float a = bias[t];
#pragma unroll
    for (int j = 0; j < 6; ++j) a += wr[j] * feat[j];
    desc[((size_t)b * D + t) * N + n] = a;
  }
}

// ---------------------------------------------------------------- generic conv1
// out[s,b,o,n] = bias[o] + sum_c w[o,c]*in(c) (+res). grid (N/256, Cout, 2*B).
__global__ __launch_bounds__(256) void k_conv(const float* __restrict__ in0,
                                              const float* __restrict__ in1,
                                              const float* __restrict__ cat0,
                                              const float* __restrict__ cat1,
                                              const float* __restrict__ w,
                                              const float* __restrict__ bias,
                                              const float* __restrict__ res,
                                              float* __restrict__ out,
                                              int Cin, int catOff,
                                              size_t in_bstr, size_t cat_bstr,
                                              int Cout) {
  int n = blockIdx.x * 256 + threadIdx.x;
  int o = blockIdx.y;
  int z = blockIdx.z;           // s*B + b
  int s = z >> 2, b = z & 3;
  const float* ip = (s ? in1 : in0) + (size_t)b * in_bstr;
  const float* wr = w + (size_t)o * Cin;
  float acc = bias[o];
#pragma unroll 4
  for (int c = 0; c < catOff; ++c) acc = fmaf(wr[c], ip[(size_t)c * N + n], acc);
  if (cat0) {
    const float* cp = (s ? cat1 : cat0) + (size_t)b * cat_bstr;
#pragma unroll 4
    for (int c = catOff; c < Cin; ++c)
      acc = fmaf(wr[c], cp[(size_t)(c - catOff) * N + n], acc);
  }
  size_t oi = ((size_t)z * Cout + o) * N + n;
  if (res) acc += res[oi];
  out[oi] = acc;
}

// ---------------------------------------------------------------- attention
// grid (N/64, NH, 2*B), 64 thr. Q/K/V/O: [2][B][D][N].
__global__ __launch_bounds__(64) void k_attn(const float* __restrict__ Q,
                                             const float* __restrict__ Kt,
                                             const float* __restrict__ Vt,
                                             float* __restrict__ O) {
  constexpr int TK = 128;
  __shared__ float kl[32][TK];
  __shared__ float vl[32][TK];
  int t = threadIdx.x;
  int n = blockIdx.x * 64 + t;
  int h = blockIdx.y;
  int z = blockIdx.z;
  const size_t base = (size_t)z * D * N;
  float q[32];
#pragma unroll
  for (int d = 0; d < 32; ++d) q[d] = Q[base + (size_t)(d * 4 + h) * N + n];
  float mx = -1e30f, l = 0.f, acc[32];
#pragma unroll
  for (int d = 0; d < 32; ++d) acc[d] = 0.f;
  const float scale = 0.17677669529663687f;  // 1/sqrt(32)
  for (int m0 = 0; m0 < N; m0 += TK) {
    __syncthreads();
    for (int i = t; i < 32 * TK; i += 64) {
      int d = i / TK, j = i % TK;
      kl[d][j] = Kt[base + (size_t)(d * 4 + h) * N + m0 + j];
      vl[d][j] = Vt[base + (size_t)(d * 4 + h) * N + m0 + j];
    }
    __syncthreads();
    for (int j = 0; j < TK; ++j) {
      float s = 0.f;
#pragma unroll
      for (int d = 0; d < 32; ++d) s += q[d] * kl[d][j];
      s *= scale;
      if (s > mx) {
        float corr = __expf(mx - s);
        l *= corr;
#pragma unroll
        for (int d = 0; d < 32; ++d) acc[d] *= corr;
        mx = s;
      }
      float p = __expf(s - mx);
      l += p;
#pragma unroll
      for (int d = 0; d < 32; ++d) acc[d] += p * vl[d][j];
    }
  }
  float inv = 1.f / l;
#pragma unroll
  for (int d = 0; d < 32; ++d) O[base + (size_t)(d * 4 + h) * N + n] = acc[d] * inv;
}

// ---------------------------------------------------------------- BN stats
// grid (256, 2). h: [2][B][256][N]. stat: [2][256][2] (mean, istd)
__global__ __launch_bounds__(256) void k_bnstat(const float* __restrict__ h,
                                                float* __restrict__ stat) {
  int c = blockIdx.x, s = blockIdx.y, t = threadIdx.x;
  __shared__ float red[256];
  const float* base = h + ((size_t)s * B * 256 + c) * N;
  float sum = 0;
  for (int b = 0; b < B; ++b)
    for (int i = t; i < N; i += 256) sum += base[(size_t)b * 256 * N + i];
  red[t] = sum; __syncthreads();
  for (int sft = 128; sft > 0; sft >>= 1) {
    if (t < sft) red[t] += red[t + sft];
    __syncthreads();
  }
  float mean = red[0] / (float)(B * N);
  __syncthreads();
  float vs = 0;
  for (int b = 0; b < B; ++b)
    for (int i = t; i < N; i += 256) {
      float d = base[(size_t)b * 256 * N + i] - mean;
      vs += d * d;
    }
  red[t] = vs; __syncthreads();
  for (int sft = 128; sft > 0; sft >>= 1) {
    if (t < sft) red[t] += red[t + sft];
    __syncthreads();
  }
  if (t == 0) {
    float var = red[0] / (float)(B * N);
    stat[(s * 256 + c) * 2 + 0] = mean;
    stat[(s * 256 + c) * 2 + 1] = 1.f / sqrtf(var + 1e-5f);
  }
}

// ---------------------------------------------------------------- BN apply + relu
__global__ __launch_bounds__(256) void k_bnrelu(float* __restrict__ h,
                                                const float* __restrict__ stat,
                                                const float* __restrict__ g,
                                                const float* __restrict__ bt) {
  int i = blockIdx.x * 256 + threadIdx.x;  // over 2*B*256*N
  int c = (i / N) % 256;
  int s = i / (B * 256 * N);
  float m = stat[(s * 256 + c) * 2 + 0];
  float is = stat[(s * 256 + c) * 2 + 1];
  float v = (h[i] - m) * is * g[c] + bt[c];
  h[i] = v > 0.f ? v : 0.f;
}

// ---------------------------------------------------------------- pairwise dist
// grid (N, B). d0,d1: [B][D][N]. la[b][m][n] = -sqrt(clip(dist2))
__global__ __launch_bounds__(256) void k_dist(const float* __restrict__ d0,
                                              const float* __restrict__ d1,
                                              float* __restrict__ la) {
  __shared__ float xm[D];
  int m = blockIdx.x, b = blockIdx.y, t = threadIdx.x;
  const float* p0 = d0 + (size_t)b * D * N;
  const float* p1 = d1 + (size_t)b * D * N;
  if (t < D) xm[t] = p0[(size_t)t * N + m];
  __syncthreads();
  float n0 = 0;
#pragma unroll 8
  for (int d = 0; d < D; ++d) n0 += xm[d] * xm[d];
  float dot[4] = {0, 0, 0, 0}, n1[4] = {0, 0, 0, 0};
  for (int d = 0; d < D; ++d) {
    float xd = xm[d];
#pragma unroll
    for (int u = 0; u < 4; ++u) {
      float v = p1[(size_t)d * N + t + u * 256];
      dot[u] += xd * v;
      n1[u] += v * v;
    }
  }
  float* row = la + ((size_t)b * N + m) * N;
#pragma unroll
  for (int u = 0; u < 4; ++u) {
    float dist2 = fmaxf(n0 + n1[u] - 2.f * dot[u], 1e-30f);
    row[t + u * 256] = -sqrtf(dist2);
  }
}

// ---------------------------------------------------------------- sinkhorn row
__global__ __launch_bounds__(256) void k_row_lse(float* __restrict__ la) {
  __shared__ float red[256];
  int t = threadIdx.x;
  float* row = la + (size_t)blockIdx.x * N;
  float v0 = row[t], v1 = row[t + 256], v2 = row[t + 512], v3 = row[t + 768];
  float mx = fmaxf(fmaxf(v0, v1), fmaxf(v2, v3));
  red[t] = mx; __syncthreads();
  for (int s = 128; s > 0; s >>= 1) {
    if (t < s) red[t] = fmaxf(red[t], red[t + s]);
    __syncthreads();
  }
  mx = red[0]; __syncthreads();
  float se = __expf(v0 - mx) + __expf(v1 - mx) + __expf(v2 - mx) + __expf(v3 - mx);
  red[t] = se; __syncthreads();
  for (int s = 128; s > 0; s >>= 1) {
    if (t < s) red[t] += red[t + s];
    __syncthreads();
  }
  float lse = mx + __logf(red[0]);
  row[t] = v0 - lse; row[t + 256] = v1 - lse;
  row[t + 512] = v2 - lse; row[t + 768] = v3 - lse;
}

// ---------------------------------------------------------------- sinkhorn col
__global__ __launch_bounds__(256) void k_col_part(const float* __restrict__ la,
                                                  float* __restrict__ pmax,
                                                  float* __restrict__ psum) {
  int t = threadIdx.x;
  int n = blockIdx.x * 256 + t;
  int p = blockIdx.y, b = blockIdx.z;
  const float* base = la + ((size_t)b * N + p * 128) * N + n;
  float mx = -1e30f, s = 0;
  for (int m = 0; m < 128; ++m) {
    float v = base[(size_t)m * N];
    if (v > mx) { s = s * __expf(mx - v) + 1.f; mx = v; }
    else s += __expf(v - mx);
  }
  pmax[((size_t)b * 8 + p) * N + n] = mx;
  psum[((size_t)b * 8 + p) * N + n] = s;
}

__global__ __launch_bounds__(256) void k_col_fin(const float* __restrict__ pmax,
                                                 const float* __restrict__ psum,
                                                 float* __restrict__ lse) {
  int i = blockIdx.x * 256 + threadIdx.x;  // over B*N
  int b = i / N, n = i % N;
  float mx = -1e30f;
  for (int p = 0; p < 8; ++p) mx = fmaxf(mx, pmax[((size_t)b * 8 + p) * N + n]);
  float s = 0;
  for (int p = 0; p < 8; ++p)
    s += psum[((size_t)b * 8 + p) * N + n] * __expf(pmax[((size_t)b * 8 + p) * N + n] - mx);
  lse[i] = mx + __logf(s);
}

__global__ __launch_bounds__(256) void k_col_sub(float* __restrict__ la,
                                                 const float* __restrict__ lse) {
  size_t i = (size_t)blockIdx.x * 256 + threadIdx.x;  // over B*N*N
  int n = (int)(i % N);
  int b = (int)(i / ((size_t)N * N));
  la[i] -= lse[(size_t)b * N + n];
}

// ---------------------------------------------------------------- rodrigues + transform
__global__ __launch_bounds__(256) void k_rod(const float* __restrict__ pose,
                                             const float* __restrict__ p3d,
                                             float* __restrict__ p3dt) {
  int b = blockIdx.y;
  int n = blockIdx.x * 256 + threadIdx.x;
  const float* aa = pose + b * 6;
  float ax = aa[0], ay = aa[1], az = aa[2];
  float th = fmaxf(sqrtf(ax * ax + ay * ay + az * az), 1e-8f);
  float rx = ax / th, ry = ay / th, rz = az / th;
  float c = cosf(th), s = sinf(th), oc = 1.f - c;
  float R00 = c + oc * rx * rx,      R01 = oc * rx * ry - s * rz, R02 = oc * rx * rz + s * ry;
  float R10 = oc * ry * rx + s * rz, R11 = c + oc * ry * ry,      R12 = oc * ry * rz - s * rx;
  float R20 = oc * rz * rx - s * ry, R21 = oc * rz * ry + s * rx, R22 = c + oc * rz * rz;
  const float* p = p3d + ((size_t)b * N + n) * 3;
  float x = p[0], y = p[1], z = p[2];
  float X = R00 * x + R01 * y + R02 * z + aa[3];
  float Y = R10 * x + R11 * y + R12 * z + aa[4];
  float Z = R20 * x + R21 * y + R22 * z + aa[5];
  float inr = 1.f / sqrtf(X * X + Y * Y + Z * Z);
  float* o = p3dt + ((size_t)b * N + n) * 3;
  o[0] = X * inr; o[1] = Y * inr; o[2] = Z * inr;
}

// ---------------------------------------------------------------- final error
// grid (N, B): per-row partial sums (deterministic, no atomics)
__global__ __launch_bounds__(256) void k_err(const float* __restrict__ la,
                                             const float* __restrict__ f2,
                                             const float* __restrict__ p3dt,
                                             float* __restrict__ rowsum) {
  __shared__ float red[256];
  int m = blockIdx.x, b = blockIdx.y, t = threadIdx.x;
  const float* row = la + ((size_t)b * N + m) * N;
  const float* f = f2 + ((size_t)b * N + m) * 3;
  float fx = f[0], fy = f[1], fz = f[2];
  float s = 0;
  for (int n = t; n < N; n += 256) {
    const float* pp = p3dt + ((size_t)b * N + n) * 3;
    float dot = fx * pp[0] + fy * pp[1] + fz * pp[2];
    s += __expf(row[n]) * (1.f - dot);
  }
  red[t] = s; __syncthreads();
  for (int sft = 128; sft > 0; sft >>= 1) {
    if (t < sft) red[t] += red[t + sft];
    __syncthreads();
  }
  if (t == 0) rowsum[(size_t)b * N + m] = red[0];
}

__global__ __launch_bounds__(256) void k_err_fin(const float* __restrict__ rowsum,
                                                 float* __restrict__ out) {
  __shared__ float red[256];
  int b = blockIdx.x, t = threadIdx.x;
  float s = 0;
  for (int i = t; i < N; i += 256) s += rowsum[(size_t)b * N + i];
  red[t] = s; __syncthreads();
  for (int sft = 128; sft > 0; sft >>= 1) {
    if (t < sft) red[t] += red[t + sft];
    __syncthreads();
  }
  if (t == 0) out[b] = red[0];
}

// ================================================================= host
extern "C" void kernel_launch(void* const* d_in, const int* in_sizes, int n_in,
                              void* d_out, int out_size, void* d_ws, size_t ws_size,
                              hipStream_t stream) {
  const float* p2d     = (const float*)d_in[0];
  const float* p3d     = (const float*)d_in[1];
  const float* pose    = (const float*)d_in[2];
  const float* enc2d_w = (const float*)d_in[3];
  const float* enc2d_b = (const float*)d_in[4];
  const float* enc3d_w = (const float*)d_in[5];
  const float* enc3d_b = (const float*)d_in[6];
  const float* proj_w  = (const float*)d_in[7];
  const float* proj_b  = (const float*)d_in[8];
  const float* merge_w = (const float*)d_in[9];
  const float* merge_b = (const float*)d_in[10];
  const float* mlp1_w  = (const float*)d_in[11];
  const float* mlp1_b  = (const float*)d_in[12];
  const float* bn_g    = (const float*)d_in[13];
  const float* bn_b    = (const float*)d_in[14];
  const float* mlp2_w  = (const float*)d_in[15];
  const float* mlp2_b  = (const float*)d_in[16];

  float* W = (float*)d_ws;
  size_t off = 0;
  auto alloc = [&](size_t nelem) { float* p = W + off; off += nelem; return p; };
  const size_t SET = (size_t)B * D * N;          // one descriptor set
  float* f2    = alloc((size_t)B * N * 3);
  float* p3dt  = alloc((size_t)B * N * 3);
  float* descA = alloc(2 * SET);
  float* descB = alloc(2 * SET);
  float* Qb    = alloc(2 * SET);
  float* Kb    = alloc(2 * SET);
  float* Vb    = alloc(2 * SET);
  float* attnb = alloc(2 * SET);
  float* msgb  = alloc(2 * SET);
  float* hb    = alloc((size_t)2 * B * 256 * N);
  float* stat  = alloc(2 * 256 * 2);
  float* la    = alloc((size_t)B * N * N);
  float* pmax  = alloc((size_t)B * 8 * N);
  float* psum  = alloc((size_t)B * 8 * N);
  float* lseb  = alloc((size_t)B * N);
  float* rowsum= alloc((size_t)B * N);
  (void)ws_size; (void)in_sizes; (void)n_in; (void)out_size;

  auto conv = [&](const float* in0, const float* in1, const float* cat0,
                  const float* cat1, const float* w, const float* bias,
                  const float* res, float* out, int Cin, int catOff,
                  size_t in_bstr, size_t cat_bstr, int Cout) {
    dim3 g(N / 256, Cout, 2 * B);
    k_conv<<<g, 256, 0, stream>>>(in0, in1, cat0, cat1, w, bias, res, out,
                                  Cin, catOff, in_bstr, cat_bstr, Cout);
  };

  k_norm2d<<<(B * N) / 256, 256, 0, stream>>>(p2d, f2);
  k_encode<<<dim3(N, B), 256, 0, stream>>>(f2, enc2d_w, enc2d_b, descA);
  k_encode<<<dim3(N, B), 256, 0, stream>>>(p3d, enc3d_w, enc3d_b, descA + SET);

  float* dc = descA;
  float* dn = descB;
  for (int i = 0; i < 6; ++i) {
    bool cross = (i & 1);
    const float* pw = proj_w + (size_t)i * 3 * D * D;
    const float* pb = proj_b + (size_t)i * 3 * D;
    float* d0 = dc;
    float* d1 = dc + SET;
    const float* sA = cross ? d1 : d0;  // src for set0
    const float* sB = cross ? d0 : d1;  // src for set1
    conv(d0, d1, nullptr, nullptr, pw,             pb,         nullptr, Qb, D, D, (size_t)D * N, 0, D);
    conv(sA, sB, nullptr, nullptr, pw + D * D,     pb + D,     nullptr, Kb, D, D, (size_t)D * N, 0, D);
    conv(sA, sB, nullptr, nullptr, pw + 2 * D * D, pb + 2 * D, nullptr, Vb, D, D, (size_t)D * N, 0, D);
    k_attn<<<dim3(N / 64, NH, 2 * B), 64, 0, stream>>>(Qb, Kb, Vb, attnb);
    conv(attnb, attnb + SET, nullptr, nullptr, merge_w + (size_t)i * D * D,
         merge_b + (size_t)i * D, nullptr, msgb, D, D, (size_t)D * N, 0, D);
    conv(d0, d1, msgb, msgb + SET, mlp1_w + (size_t)i * 256 * 256,
         mlp1_b + (size_t)i * 256, nullptr, hb, 256, 128, (size_t)D * N,
         (size_t)D * N, 256);
    k_bnstat<<<dim3(256, 2), 256, 0, stream>>>(hb, stat);
    k_bnrelu<<<(2 * B * 256 * N) / 256, 256, 0, stream>>>(
        hb, stat, bn_g + (size_t)i * 256, bn_b + (size_t)i * 256);
    conv(hb, hb + (size_t)B * 256 * N, nullptr, nullptr,
         mlp2_w + (size_t)i * D * 256, mlp2_b + (size_t)i * D, dc, dn, 256, 256,
         (size_t)256 * N, 0, D);
    float* tmp = dc; dc = dn; dn = tmp;
  }

  k_dist<<<dim3(N, B), 256, 0, stream>>>(dc, dc + SET, la);
  for (int it = 0; it < 10; ++it) {
    k_row_lse<<<B * N, 256, 0, stream>>>(la);
    k_col_part<<<dim3(N / 256, 8, B), 256, 0, stream>>>(la, pmax, psum);
    k_col_fin<<<(B * N) / 256, 256, 0, stream>>>(pmax, psum, lseb);
    k_col_sub<<<(int)(((size_t)B * N * N) / 256), 256, 0, stream>>>(la, lseb);
  }
  k_rod<<<dim3(N / 256, B), 256, 0, stream>>>(pose, p3d, p3dt);
  k_err<<<dim3(N, B), 256, 0, stream>>>(la, f2, p3dt, rowsum);
  k_err_fin<<<B, 256, 0, stream>>>(rowsum, (float*)d_out);
}

// Round 2
// 2428.766 us; speedup vs baseline: 2.1719x; 2.1719x over previous
//
#include <hip/hip_runtime.h>
#include <hip/hip_bf16.h>

constexpr int B   = 4;
constexpr int N   = 1024;
constexpr int D   = 128;
constexpr int KNN = 10;
constexpr int NH  = 4;

// ---------------------------------------------------------------- norm p2d
__global__ __launch_bounds__(256) void k_norm2d(const float* __restrict__ p2d,
                                                float* __restrict__ f2) {
  int i = blockIdx.x * 256 + threadIdx.x;  // over B*N
  const float* p = p2d + (size_t)i * 3;
  float x = p[0], y = p[1], z = p[2];
  float inr = 1.f / sqrtf(x * x + y * y + z * z);
  float* o = f2 + (size_t)i * 3;
  o[0] = x * inr; o[1] = y * inr; o[2] = z * inr;
}

// ---------------------------------------------------------------- KNN encode
__global__ __launch_bounds__(256) void k_encode(const float* __restrict__ pts,
                                                const float* __restrict__ w,
                                                const float* __restrict__ bias,
                                                float* __restrict__ desc) {
  __shared__ float P[N][3];
  __shared__ float xx[N];
  __shared__ float dist[N];
  __shared__ float rv[256];
  __shared__ int   ri[256];
  __shared__ float feat[6];
  __shared__ int   nidx[KNN];
  int t = threadIdx.x;
  int n = blockIdx.x, b = blockIdx.y;
  const float* pb = pts + (size_t)b * N * 3;
  for (int i = t; i < N; i += 256) {
    float x = pb[i * 3 + 0], y = pb[i * 3 + 1], z = pb[i * 3 + 2];
    P[i][0] = x; P[i][1] = y; P[i][2] = z;
    xx[i] = x * x + y * y + z * z;
  }
  __syncthreads();
  float cx = P[n][0], cy = P[n][1], cz = P[n][2], cxx = xx[n];
  for (int i = t; i < N; i += 256) {
    float ip = cx * P[i][0] + cy * P[i][1] + cz * P[i][2];
    dist[i] = 2.f * ip - cxx - xx[i];
  }
  __syncthreads();
  for (int kk = 0; kk < KNN; ++kk) {
    float bv = -3.0e38f; int bi = N;
    for (int i = t; i < N; i += 256) {
      float v = dist[i];
      if (v > bv) { bv = v; bi = i; }
    }
    rv[t] = bv; ri[t] = bi;
    __syncthreads();
    for (int s = 128; s > 0; s >>= 1) {
      if (t < s) {
        float v2 = rv[t + s]; int i2 = ri[t + s];
        if (v2 > rv[t] || (v2 == rv[t] && i2 < ri[t])) { rv[t] = v2; ri[t] = i2; }
      }
      __syncthreads();
    }
    if (t == 0) { nidx[kk] = ri[0]; dist[ri[0]] = -3.0e38f; }
    __syncthreads();
  }
  if (t == 0) {
    float sx = 0, sy = 0, sz = 0;
    for (int kk = 0; kk < KNN; ++kk) {
      int i = nidx[kk];
      sx += P[i][0]; sy += P[i][1]; sz += P[i][2];
    }
    const float invk = 1.f / KNN;
    feat[0] = sx * invk - cx; feat[1] = sy * invk - cy; feat[2] = sz * invk - cz;
    feat[3] = cx; feat[4] = cy; feat[5] = cz;
  }
  __syncthreads();
  if (t < D) {
    const float* wr = w + t * 6;
    float a = bias[t];
#pragma unroll
    for (int j = 0; j < 6; ++j) a += wr[j] * feat[j];
    desc[((size_t)b * D + t) * N + n] = a;
  }
}

// ---------------------------------------------------------------- generic conv1 (4-o unroll)
// grid (N/256, Cout/4, 2*B)
__global__ __launch_bounds__(256) void k_conv(const float* __restrict__ in0,
                                              const float* __restrict__ in1,
                                              const float* __restrict__ cat0,
                                              const float* __restrict__ cat1,
                                              const float* __restrict__ w,
                                              const float* __restrict__ bias,
                                              const float* __restrict__ res,
                                              float* __restrict__ out,
                                              int Cin, int catOff,
                                              size_t in_bstr, size_t cat_bstr,
                                              int Cout) {
  int n = blockIdx.x * 256 + threadIdx.x;
  int o0 = blockIdx.y * 4;
  int z = blockIdx.z;           // s*B + b
  int s = z >> 2, b = z & 3;
  const float* ip = (s ? in1 : in0) + (size_t)b * in_bstr;
  const float* w0 = w + (size_t)o0 * Cin;
  float a0 = bias[o0], a1 = bias[o0 + 1], a2 = bias[o0 + 2], a3 = bias[o0 + 3];
#pragma unroll 4
  for (int c = 0; c < catOff; ++c) {
    float v = ip[(size_t)c * N + n];
    a0 = fmaf(w0[c], v, a0);
    a1 = fmaf(w0[Cin + c], v, a1);
    a2 = fmaf(w0[2 * Cin + c], v, a2);
    a3 = fmaf(w0[3 * Cin + c], v, a3);
  }
  if (cat0) {
    const float* cp = (s ? cat1 : cat0) + (size_t)b * cat_bstr;
#pragma unroll 4
    for (int c = catOff; c < Cin; ++c) {
      float v = cp[(size_t)(c - catOff) * N + n];
      a0 = fmaf(w0[c], v, a0);
      a1 = fmaf(w0[Cin + c], v, a1);
      a2 = fmaf(w0[2 * Cin + c], v, a2);
      a3 = fmaf(w0[3 * Cin + c], v, a3);
    }
  }
  size_t ob = ((size_t)z * Cout + o0) * N + n;
  if (res) {
    a0 += res[ob]; a1 += res[ob + N]; a2 += res[ob + 2 * N]; a3 += res[ob + 3 * N];
  }
  out[ob] = a0; out[ob + N] = a1; out[ob + 2 * N] = a2; out[ob + 3 * N] = a3;
}

// ---------------------------------------------------------------- attention v2
// grid (N/64, NH, 2*B), 256 thr = 4 waves. Wave s handles keys [s*256,(s+1)*256)
// for the block's 64 queries. K/V staged in per-wave LDS subchunks of 32 keys,
// layout [j][68] (K d=0..31 at slot d, V at slot 32+d). Partials merged in-block.
__global__ __launch_bounds__(256) void k_attn(const float* __restrict__ Q,
                                              const float* __restrict__ Kt,
                                              const float* __restrict__ Vt,
                                              float* __restrict__ O) {
  __shared__ float pool[4 * 32 * 68];     // kv staging, aliased as merge acc
  __shared__ float ms_[4][64], ls_[4][64];
#define KV(s, j, slot) pool[(((s) * 32 + (j)) * 68) + (slot)]
#define ACC(ss, q, d)  pool[(((ss) * 64 + (q)) * 34) + (d)]
  int t = threadIdx.x;
  int lq = t & 63, s = t >> 6;
  int n = blockIdx.x * 64 + lq;
  int h = blockIdx.y;
  int z = blockIdx.z;
  const size_t base = (size_t)z * (size_t)(D * N);
  const float* Kb = Kt + base;
  const float* Vb = Vt + base;
  float q[32];
#pragma unroll
  for (int d = 0; d < 32; ++d) q[d] = Q[base + (size_t)(d * 4 + h) * N + n];
  float mx = -1e30f, l = 0.f, acc[32];
#pragma unroll
  for (int d = 0; d < 32; ++d) acc[d] = 0.f;
  const float scale = 0.17677669529663687f;  // 1/sqrt(32)

  for (int c = 0; c < 256; c += 32) {
    int k0 = s * 256 + c;
    __syncthreads();
    // stage 32 keys x (32 K + 32 V) into this wave's region, coalesced
    {
      int j = lq & 31;
      int half = lq >> 5;  // 0 or 1
#pragma unroll 4
      for (int it = 0; it < 32; ++it) {
        int slot = it * 2 + half;
        const float* src = (it < 16) ? (Kb + (size_t)(slot * 4 + h) * N)
                                     : (Vb + (size_t)((slot - 32) * 4 + h) * N);
        KV(s, j, slot) = src[k0 + j];
      }
    }
    __syncthreads();
    // scores for the 32 staged keys
    float sc[32];
    float cmax = -1e30f;
    for (int j = 0; j < 32; ++j) {
      float v = 0.f;
#pragma unroll
      for (int d0 = 0; d0 < 32; d0 += 4) {
        const float4 k4 = *(const float4*)&KV(s, j, d0);
        v += q[d0] * k4.x + q[d0 + 1] * k4.y + q[d0 + 2] * k4.z + q[d0 + 3] * k4.w;
      }
      v *= scale;
      sc[j] = v;
      cmax = fmaxf(cmax, v);
    }
    float mnew = fmaxf(mx, cmax);
    float corr = __expf(mx - mnew);
    l *= corr;
#pragma unroll
    for (int d = 0; d < 32; ++d) acc[d] *= corr;
    mx = mnew;
    for (int j = 0; j < 32; ++j) {
      float p = __expf(sc[j] - mx);
      l += p;
#pragma unroll
      for (int d0 = 0; d0 < 32; d0 += 4) {
        const float4 v4 = *(const float4*)&KV(s, j, 32 + d0);
        acc[d0]     = fmaf(p, v4.x, acc[d0]);
        acc[d0 + 1] = fmaf(p, v4.y, acc[d0 + 1]);
        acc[d0 + 2] = fmaf(p, v4.z, acc[d0 + 2]);
        acc[d0 + 3] = fmaf(p, v4.w, acc[d0 + 3]);
      }
    }
  }
  // merge 4 partials per query
  __syncthreads();
  ms_[s][lq] = mx; ls_[s][lq] = l;
#pragma unroll
  for (int d = 0; d < 32; ++d) ACC(s, lq, d) = acc[d];
  __syncthreads();
  int qq = t >> 2, g = t & 3;
  float M = -1e30f;
#pragma unroll
  for (int ss = 0; ss < 4; ++ss) M = fmaxf(M, ms_[ss][qq]);
  float wgt[4], L = 0.f;
#pragma unroll
  for (int ss = 0; ss < 4; ++ss) {
    wgt[ss] = __expf(ms_[ss][qq] - M);
    L += ls_[ss][qq] * wgt[ss];
  }
  float invL = 1.f / L;
  int n2 = blockIdx.x * 64 + qq;
#pragma unroll
  for (int k = 0; k < 8; ++k) {
    int d = g * 8 + k;
    float o = 0.f;
#pragma unroll
    for (int ss = 0; ss < 4; ++ss) o += ACC(ss, qq, d) * wgt[ss];
    O[base + (size_t)(d * 4 + h) * N + n2] = o * invL;
  }
#undef KV
#undef ACC
}

// ---------------------------------------------------------------- BN stats
__global__ __launch_bounds__(256) void k_bnstat(const float* __restrict__ h,
                                                float* __restrict__ stat) {
  int c = blockIdx.x, s = blockIdx.y, t = threadIdx.x;
  __shared__ float red[256];
  const float* base = h + ((size_t)s * B * 256 + c) * N;
  float sum = 0;
  for (int b = 0; b < B; ++b)
    for (int i = t; i < N; i += 256) sum += base[(size_t)b * 256 * N + i];
  red[t] = sum; __syncthreads();
  for (int sft = 128; sft > 0; sft >>= 1) {
    if (t < sft) red[t] += red[t + sft];
    __syncthreads();
  }
  float mean = red[0] / (float)(B * N);
  __syncthreads();
  float vs = 0;
  for (int b = 0; b < B; ++b)
    for (int i = t; i < N; i += 256) {
      float d = base[(size_t)b * 256 * N + i] - mean;
      vs += d * d;
    }
  red[t] = vs; __syncthreads();
  for (int sft = 128; sft > 0; sft >>= 1) {
    if (t < sft) red[t] += red[t + sft];
    __syncthreads();
  }
  if (t == 0) {
    float var = red[0] / (float)(B * N);
    stat[(s * 256 + c) * 2 + 0] = mean;
    stat[(s * 256 + c) * 2 + 1] = 1.f / sqrtf(var + 1e-5f);
  }
}

// ---------------------------------------------------------------- BN apply + relu
__global__ __launch_bounds__(256) void k_bnrelu(float* __restrict__ h,
                                                const float* __restrict__ stat,
                                                const float* __restrict__ g,
                                                const float* __restrict__ bt) {
  int i = blockIdx.x * 256 + threadIdx.x;
  int c = (i / N) % 256;
  int s = i / (B * 256 * N);
  float m = stat[(s * 256 + c) * 2 + 0];
  float is = stat[(s * 256 + c) * 2 + 1];
  float v = (h[i] - m) * is * g[c] + bt[c];
  h[i] = v > 0.f ? v : 0.f;
}

// ---------------------------------------------------------------- pairwise dist (8-m tile)
// grid (N/8, B)
__global__ __launch_bounds__(256) void k_dist(const float* __restrict__ d0,
                                              const float* __restrict__ d1,
                                              float* __restrict__ la) {
  __shared__ float xm[8][128];
  __shared__ float n0s[8];
  int m0 = blockIdx.x * 8, b = blockIdx.y, t = threadIdx.x;
  const float* p0 = d0 + (size_t)b * D * N;
  const float* p1 = d1 + (size_t)b * D * N;
  for (int i = t; i < 8 * 128; i += 256) {
    int mm = i >> 7, d = i & 127;
    xm[mm][d] = p0[(size_t)d * N + m0 + mm];
  }
  __syncthreads();
  if (t < 8) {
    float s = 0;
    for (int d = 0; d < 128; ++d) s += xm[t][d] * xm[t][d];
    n0s[t] = s;
  }
  __syncthreads();
  float dot[8][4] = {{0}};
  float n1[4] = {0, 0, 0, 0};
  for (int d = 0; d < 128; ++d) {
    float v[4];
#pragma unroll
    for (int u = 0; u < 4; ++u) {
      v[u] = p1[(size_t)d * N + t + u * 256];
      n1[u] = fmaf(v[u], v[u], n1[u]);
    }
#pragma unroll
    for (int mm = 0; mm < 8; ++mm) {
      float x = xm[mm][d];
#pragma unroll
      for (int u = 0; u < 4; ++u) dot[mm][u] = fmaf(x, v[u], dot[mm][u]);
    }
  }
  for (int mm = 0; mm < 8; ++mm) {
    float* row = la + ((size_t)b * N + m0 + mm) * N;
#pragma unroll
    for (int u = 0; u < 4; ++u) {
      float dist2 = fmaxf(n0s[mm] + n1[u] - 2.f * dot[mm][u], 1e-30f);
      row[t + u * 256] = -sqrtf(dist2);
    }
  }
}

// ---------------------------------------------------------------- sinkhorn row (+ pending col sub)
__global__ __launch_bounds__(256) void k_row_lse(float* __restrict__ la,
                                                 const float* __restrict__ colse) {
  __shared__ float red[256];
  int t = threadIdx.x;
  int bm = blockIdx.x;              // over B*N
  int b = bm >> 10;
  float* row = la + (size_t)bm * N;
  float v0 = row[t], v1 = row[t + 256], v2 = row[t + 512], v3 = row[t + 768];
  if (colse) {
    const float* cl = colse + (size_t)b * N;
    v0 -= cl[t]; v1 -= cl[t + 256]; v2 -= cl[t + 512]; v3 -= cl[t + 768];
  }
  float mx = fmaxf(fmaxf(v0, v1), fmaxf(v2, v3));
  red[t] = mx; __syncthreads();
  for (int s = 128; s > 0; s >>= 1) {
    if (t < s) red[t] = fmaxf(red[t], red[t + s]);
    __syncthreads();
  }
  mx = red[0]; __syncthreads();
  float se = __expf(v0 - mx) + __expf(v1 - mx) + __expf(v2 - mx) + __expf(v3 - mx);
  red[t] = se; __syncthreads();
  for (int s = 128; s > 0; s >>= 1) {
    if (t < s) red[t] += red[t + s];
    __syncthreads();
  }
  float lse = mx + __logf(red[0]);
  row[t] = v0 - lse; row[t + 256] = v1 - lse;
  row[t + 512] = v2 - lse; row[t + 768] = v3 - lse;
}

// ---------------------------------------------------------------- sinkhorn col
__global__ __launch_bounds__(256) void k_col_part(const float* __restrict__ la,
                                                  float* __restrict__ pmax,
                                                  float* __restrict__ psum) {
  int t = threadIdx.x;
  int n = blockIdx.x * 256 + t;
  int p = blockIdx.y, b = blockIdx.z;
  const float* base = la + ((size_t)b * N + p * 128) * N + n;
  float mx = -1e30f, s = 0;
  for (int m = 0; m < 128; ++m) {
    float v = base[(size_t)m * N];
    if (v > mx) { s = s * __expf(mx - v) + 1.f; mx = v; }
    else s += __expf(v - mx);
  }
  pmax[((size_t)b * 8 + p) * N + n] = mx;
  psum[((size_t)b * 8 + p) * N + n] = s;
}

__global__ __launch_bounds__(256) void k_col_fin(const float* __restrict__ pmax,
                                                 const float* __restrict__ psum,
                                                 float* __restrict__ lse) {
  int i = blockIdx.x * 256 + threadIdx.x;  // over B*N
  int b = i / N, n = i % N;
  float mx = -1e30f;
  for (int p = 0; p < 8; ++p) mx = fmaxf(mx, pmax[((size_t)b * 8 + p) * N + n]);
  float s = 0;
  for (int p = 0; p < 8; ++p)
    s += psum[((size_t)b * 8 + p) * N + n] * __expf(pmax[((size_t)b * 8 + p) * N + n] - mx);
  lse[i] = mx + __logf(s);
}

// ---------------------------------------------------------------- rodrigues + transform
__global__ __launch_bounds__(256) void k_rod(const float* __restrict__ pose,
                                             const float* __restrict__ p3d,
                                             float* __restrict__ p3dt) {
  int b = blockIdx.y;
  int n = blockIdx.x * 256 + threadIdx.x;
  const float* aa = pose + b * 6;
  float ax = aa[0], ay = aa[1], az = aa[2];
  float th = fmaxf(sqrtf(ax * ax + ay * ay + az * az), 1e-8f);
  float rx = ax / th, ry = ay / th, rz = az / th;
  float c = cosf(th), s = sinf(th), oc = 1.f - c;
  float R00 = c + oc * rx * rx,      R01 = oc * rx * ry - s * rz, R02 = oc * rx * rz + s * ry;
  float R10 = oc * ry * rx + s * rz, R11 = c + oc * ry * ry,      R12 = oc * ry * rz - s * rx;
  float R20 = oc * rz * rx - s * ry, R21 = oc * rz * ry + s * rx, R22 = c + oc * rz * rz;
  const float* p = p3d + ((size_t)b * N + n) * 3;
  float x = p[0], y = p[1], z = p[2];
  float X = R00 * x + R01 * y + R02 * z + aa[3];
  float Y = R10 * x + R11 * y + R12 * z + aa[4];
  float Z = R20 * x + R21 * y + R22 * z + aa[5];
  float inr = 1.f / sqrtf(X * X + Y * Y + Z * Z);
  float* o = p3dt + ((size_t)b * N + n) * 3;
  o[0] = X * inr; o[1] = Y * inr; o[2] = Z * inr;
}

// ---------------------------------------------------------------- final error (applies pending col sub)
__global__ __launch_bounds__(256) void k_err(const float* __restrict__ la,
                                             const float* __restrict__ colse,
                                             const float* __restrict__ f2,
                                             const float* __restrict__ p3dt,
                                             float* __restrict__ rowsum) {
  __shared__ float red[256];
  int m = blockIdx.x, b = blockIdx.y, t = threadIdx.x;
  const float* row = la + ((size_t)b * N + m) * N;
  const float* cl = colse + (size_t)b * N;
  const float* f = f2 + ((size_t)b * N + m) * 3;
  float fx = f[0], fy = f[1], fz = f[2];
  float s = 0;
  for (int n = t; n < N; n += 256) {
    const float* pp = p3dt + ((size_t)b * N + n) * 3;
    float dot = fx * pp[0] + fy * pp[1] + fz * pp[2];
    s += __expf(row[n] - cl[n]) * (1.f - dot);
  }
  red[t] = s; __syncthreads();
  for (int sft = 128; sft > 0; sft >>= 1) {
    if (t < sft) red[t] += red[t + sft];
    __syncthreads();
  }
  if (t == 0) rowsum[(size_t)b * N + m] = red[0];
}

__global__ __launch_bounds__(256) void k_err_fin(const float* __restrict__ rowsum,
                                                 float* __restrict__ out) {
  __shared__ float red[256];
  int b = blockIdx.x, t = threadIdx.x;
  float s = 0;
  for (int i = t; i < N; i += 256) s += rowsum[(size_t)b * N + i];
  red[t] = s; __syncthreads();
  for (int sft = 128; sft > 0; sft >>= 1) {
    if (t < sft) red[t] += red[t + sft];
    __syncthreads();
  }
  if (t == 0) out[b] = red[0];
}

// ================================================================= host
extern "C" void kernel_launch(void* const* d_in, const int* in_sizes, int n_in,
                              void* d_out, int out_size, void* d_ws, size_t ws_size,
                              hipStream_t stream) {
  const float* p2d     = (const float*)d_in[0];
  const float* p3d     = (const float*)d_in[1];
  const float* pose    = (const float*)d_in[2];
  const float* enc2d_w = (const float*)d_in[3];
  const float* enc2d_b = (const float*)d_in[4];
  const float* enc3d_w = (const float*)d_in[5];
  const float* enc3d_b = (const float*)d_in[6];
  const float* proj_w  = (const float*)d_in[7];
  const float* proj_b  = (const float*)d_in[8];
  const float* merge_w = (const float*)d_in[9];
  const float* merge_b = (const float*)d_in[10];
  const float* mlp1_w  = (const float*)d_in[11];
  const float* mlp1_b  = (const float*)d_in[12];
  const float* bn_g    = (const float*)d_in[13];
  const float* bn_b    = (const float*)d_in[14];
  const float* mlp2_w  = (const float*)d_in[15];
  const float* mlp2_b  = (const float*)d_in[16];

  float* W = (float*)d_ws;
  size_t off = 0;
  auto alloc = [&](size_t nelem) { float* p = W + off; off += nelem; return p; };
  const size_t SET = (size_t)B * D * N;
  float* f2    = alloc((size_t)B * N * 3);
  float* p3dt  = alloc((size_t)B * N * 3);
  float* descA = alloc(2 * SET);
  float* descB = alloc(2 * SET);
  float* Qb    = alloc(2 * SET);
  float* Kb    = alloc(2 * SET);
  float* Vb    = alloc(2 * SET);
  float* attnb = alloc(2 * SET);
  float* msgb  = alloc(2 * SET);
  float* hb    = alloc((size_t)2 * B * 256 * N);
  float* stat  = alloc(2 * 256 * 2);
  float* la    = alloc((size_t)B * N * N);
  float* pmax  = alloc((size_t)B * 8 * N);
  float* psum  = alloc((size_t)B * 8 * N);
  float* lseb  = alloc((size_t)B * N);
  float* rowsum= alloc((size_t)B * N);
  (void)ws_size; (void)in_sizes; (void)n_in; (void)out_size;

  auto conv = [&](const float* in0, const float* in1, const float* cat0,
                  const float* cat1, const float* w, const float* bias,
                  const float* res, float* out, int Cin, int catOff,
                  size_t in_bstr, size_t cat_bstr, int Cout) {
    dim3 g(N / 256, Cout / 4, 2 * B);
    k_conv<<<g, 256, 0, stream>>>(in0, in1, cat0, cat1, w, bias, res, out,
                                  Cin, catOff, in_bstr, cat_bstr, Cout);
  };

  k_norm2d<<<(B * N) / 256, 256, 0, stream>>>(p2d, f2);
  k_encode<<<dim3(N, B), 256, 0, stream>>>(f2, enc2d_w, enc2d_b, descA);
  k_encode<<<dim3(N, B), 256, 0, stream>>>(p3d, enc3d_w, enc3d_b, descA + SET);

  float* dc = descA;
  float* dn = descB;
  for (int i = 0; i < 6; ++i) {
    bool cross = (i & 1);
    const float* pw = proj_w + (size_t)i * 3 * D * D;
    const float* pb = proj_b + (size_t)i * 3 * D;
    float* d0 = dc;
    float* d1 = dc + SET;
    const float* sA = cross ? d1 : d0;
    const float* sB = cross ? d0 : d1;
    conv(d0, d1, nullptr, nullptr, pw,             pb,         nullptr, Qb, D, D, (size_t)D * N, 0, D);
    conv(sA, sB, nullptr, nullptr, pw + D * D,     pb + D,     nullptr, Kb, D, D, (size_t)D * N, 0, D);
    conv(sA, sB, nullptr, nullptr, pw + 2 * D * D, pb + 2 * D, nullptr, Vb, D, D, (size_t)D * N, 0, D);
    k_attn<<<dim3(N / 64, NH, 2 * B), 256, 0, stream>>>(Qb, Kb, Vb, attnb);
    conv(attnb, attnb + SET, nullptr, nullptr, merge_w + (size_t)i * D * D,
         merge_b + (size_t)i * D, nullptr, msgb, D, D, (size_t)D * N, 0, D);
    conv(d0, d1, msgb, msgb + SET, mlp1_w + (size_t)i * 256 * 256,
         mlp1_b + (size_t)i * 256, nullptr, hb, 256, 128, (size_t)D * N,
         (size_t)D * N, 256);
    k_bnstat<<<dim3(256, 2), 256, 0, stream>>>(hb, stat);
    k_bnrelu<<<(2 * B * 256 * N) / 256, 256, 0, stream>>>(
        hb, stat, bn_g + (size_t)i * 256, bn_b + (size_t)i * 256);
    conv(hb, hb + (size_t)B * 256 * N, nullptr, nullptr,
         mlp2_w + (size_t)i * D * 256, mlp2_b + (size_t)i * D, dc, dn, 256, 256,
         (size_t)256 * N, 0, D);
    float* tmp = dc; dc = dn; dn = tmp;
  }

  k_dist<<<dim3(N / 8, B), 256, 0, stream>>>(dc, dc + SET, la);
  for (int it = 0; it < 10; ++it) {
    k_row_lse<<<B * N, 256, 0, stream>>>(la, it == 0 ? nullptr : lseb);
    k_col_part<<<dim3(N / 256, 8, B), 256, 0, stream>>>(la, pmax, psum);
    k_col_fin<<<(B * N) / 256, 256, 0, stream>>>(pmax, psum, lseb);
  }
  k_rod<<<dim3(N / 256, B), 256, 0, stream>>>(pose, p3d, p3dt);
  k_err<<<dim3(N, B), 256, 0, stream>>>(la, lseb, f2, p3dt, rowsum);
  k_err_fin<<<B, 256, 0, stream>>>(rowsum, (float*)d_out);
}